// Round 3
// baseline (534.862 us; speedup 1.0000x reference)
//
#include <hip/hip_runtime.h>
#include <math.h>

#define TPB 256

__device__ __forceinline__ float bilin(const float* __restrict__ mb,
                                       float px, float vy0, float vy1,
                                       int ry0, int ry1, int Hm, int Wm) {
    float fx = floorf(px);
    int ix = (int)fx;
    float wx1 = px - fx;
    float wx0 = 1.f - wx1;
    float vx0 = (ix >= 0 && ix < Wm) ? wx0 : 0.f;
    float vx1 = (ix + 1 >= 0 && ix + 1 < Wm) ? wx1 : 0.f;
    int rx0 = min(max(ix, 0), Wm - 1);
    int rx1 = min(max(ix + 1, 0), Wm - 1);
    float top = mb[ry0 * Wm + rx0] * vx0 + mb[ry0 * Wm + rx1] * vx1;
    float bot = mb[ry1 * Wm + rx0] * vx0 + mb[ry1 * Wm + rx1] * vx1;
    return top * vy0 + bot * vy1;
}

__device__ __forceinline__ float sample_one(const float* __restrict__ mb,
                                            float px, float py, int Hm, int Wm) {
    if (py <= -1.f || py >= (float)Hm || px <= -1.f || px >= (float)Wm) return 0.f;
    float fy = floorf(py);
    int iy = (int)fy;
    float wy1 = py - fy, wy0 = 1.f - wy1;
    float vy0 = (iy >= 0 && iy < Hm) ? wy0 : 0.f;
    float vy1 = (iy + 1 >= 0 && iy + 1 < Hm) ? wy1 : 0.f;
    int ry0 = min(max(iy, 0), Hm - 1);
    int ry1 = min(max(iy + 1, 0), Hm - 1);
    return bilin(mb, px, vy0, vy1, ry0, ry1, Hm, Wm);
}

__global__ void paste(const float* __restrict__ masks,
                      const float* __restrict__ boxes,
                      const int* __restrict__ p_img_h,
                      const int* __restrict__ p_img_w,
                      const int* __restrict__ p_in_h,
                      const int* __restrict__ p_in_w,
                      float* __restrict__ out,
                      int HW, int Hm, int Wm) {
    __shared__ float4 sP;
    const int n = blockIdx.z;
    const int img_w = p_img_w[0];          // uniform scalar load

    if (threadIdx.x == 0) {
        float fw = (float)img_w, fh = (float)p_img_h[0];
        float sx = fw / (float)p_in_w[0];
        float sy = fh / (float)p_in_h[0];
        float x0 = fminf(fmaxf(boxes[4*n+0] * sx, 0.f), fw);
        float y0 = fminf(fmaxf(boxes[4*n+1] * sy, 0.f), fh);
        float x1 = fminf(fmaxf(boxes[4*n+2] * sx, 0.f), fw);
        float y1 = fminf(fmaxf(boxes[4*n+3] * sy, 0.f), fh);
        sP = make_float4(x0, y0, (float)Wm / (x1 - x0), (float)Hm / (y1 - y0));
    }
    __syncthreads();
    const float4 P = sP;

    int q = blockIdx.x * blockDim.x + threadIdx.x;
    int base = q * 4;
    if (base >= HW) return;
    int y = base / img_w;
    int x = base - y * img_w;
    float* optr = out + (size_t)n * HW + base;
    const float* mb = masks + (size_t)n * Hm * Wm;

    bool aligned = (((size_t)optr & 15) == 0);
    if (aligned && (x + 3 < img_w) && (base + 3 < HW)) {
        float py = ((float)y + 0.5f - P.y) * P.w - 0.5f;
        float px0 = ((float)x + 0.5f - P.x) * P.z - 0.5f;
        float px3 = px0 + 3.f * P.z;
        if (py <= -1.f || py >= (float)Hm || px3 <= -1.f || px0 >= (float)Wm) {
            *(float4*)optr = make_float4(0.f, 0.f, 0.f, 0.f);
        } else {
            float fy = floorf(py);
            int iy = (int)fy;
            float wy1 = py - fy, wy0 = 1.f - wy1;
            float vy0 = (iy >= 0 && iy < Hm) ? wy0 : 0.f;
            float vy1 = (iy + 1 >= 0 && iy + 1 < Hm) ? wy1 : 0.f;
            int ry0 = min(max(iy, 0), Hm - 1);
            int ry1 = min(max(iy + 1, 0), Hm - 1);
            float4 r;
            r.x = bilin(mb, px0, vy0, vy1, ry0, ry1, Hm, Wm);
            r.y = bilin(mb, px0 + P.z, vy0, vy1, ry0, ry1, Hm, Wm);
            r.z = bilin(mb, px0 + 2.f * P.z, vy0, vy1, ry0, ry1, Hm, Wm);
            r.w = bilin(mb, px3, vy0, vy1, ry0, ry1, Hm, Wm);
            *(float4*)optr = r;
        }
    } else {
        // generic path: row-crossing quads, tails, unaligned
        int yy = y, xx = x;
        for (int i = 0; i < 4; ++i) {
            if (base + i >= HW) break;
            float py = ((float)yy + 0.5f - P.y) * P.w - 0.5f;
            float px = ((float)xx + 0.5f - P.x) * P.z - 0.5f;
            optr[i] = sample_one(mb, px, py, Hm, Wm);
            xx++;
            if (xx >= img_w) { xx = 0; yy++; }
        }
    }
}

extern "C" void kernel_launch(void* const* d_in, const int* in_sizes, int n_in,
                              void* d_out, int out_size, void* d_ws, size_t ws_size,
                              hipStream_t stream) {
    const float* masks  = (const float*)d_in[0];
    const float* boxes  = (const float*)d_in[1];
    const int* p_img_h  = (const int*)d_in[2];
    const int* p_img_w  = (const int*)d_in[3];
    const int* p_in_h   = (const int*)d_in[4];
    const int* p_in_w   = (const int*)d_in[5];

    int N = in_sizes[1] / 4;                 // boxes = [N,4]
    int mask_hw = in_sizes[0] / N;           // Hm*Wm
    int Wm = (int)(sqrtf((float)mask_hw) + 0.5f);
    int Hm = mask_hw / Wm;
    int HW = out_size / N;                   // img_h * img_w

    int nquad = (HW + 3) / 4;
    dim3 grid((nquad + TPB - 1) / TPB, 1, N);
    hipLaunchKernelGGL(paste, grid, dim3(TPB), 0, stream,
                       masks, boxes, p_img_h, p_img_w, p_in_h, p_in_w,
                       (float*)d_out, HW, Hm, Wm);
}

// Round 4
// 528.527 us; speedup vs baseline: 1.0120x; 1.0120x over previous
//
#include <hip/hip_runtime.h>
#include <math.h>

#define TPB 256

__device__ __forceinline__ float bilin(const float* __restrict__ mb,
                                       float px, float vy0, float vy1,
                                       int ry0, int ry1, int Hm, int Wm) {
    float fx = floorf(px);
    int ix = (int)fx;
    float wx1 = px - fx;
    float wx0 = 1.f - wx1;
    float vx0 = (ix >= 0 && ix < Wm) ? wx0 : 0.f;
    float vx1 = (ix + 1 >= 0 && ix + 1 < Wm) ? wx1 : 0.f;
    int rx0 = min(max(ix, 0), Wm - 1);
    int rx1 = min(max(ix + 1, 0), Wm - 1);
    float top = mb[ry0 * Wm + rx0] * vx0 + mb[ry0 * Wm + rx1] * vx1;
    float bot = mb[ry1 * Wm + rx0] * vx0 + mb[ry1 * Wm + rx1] * vx1;
    return top * vy0 + bot * vy1;
}

__device__ __forceinline__ float sample_one(const float* __restrict__ mb,
                                            float px, float py, int Hm, int Wm) {
    if (py <= -1.f || py >= (float)Hm || px <= -1.f || px >= (float)Wm) return 0.f;
    float fy = floorf(py);
    int iy = (int)fy;
    float wy1 = py - fy, wy0 = 1.f - wy1;
    float vy0 = (iy >= 0 && iy < Hm) ? wy0 : 0.f;
    float vy1 = (iy + 1 >= 0 && iy + 1 < Hm) ? wy1 : 0.f;
    int ry0 = min(max(iy, 0), Hm - 1);
    int ry1 = min(max(iy + 1, 0), Hm - 1);
    return bilin(mb, px, vy0, vy1, ry0, ry1, Hm, Wm);
}

// 8 pixels (two float4 stores) per thread.
__global__ __launch_bounds__(TPB) void paste(const float* __restrict__ masks,
                      const float* __restrict__ boxes,
                      const int* __restrict__ p_img_h,
                      const int* __restrict__ p_img_w,
                      const int* __restrict__ p_in_h,
                      const int* __restrict__ p_in_w,
                      float* __restrict__ out,
                      int HW, int Hm, int Wm) {
    __shared__ float4 sP;
    __shared__ float sInvW;
    const int n = blockIdx.z;
    const int img_w = p_img_w[0];          // uniform scalar load

    if (threadIdx.x == 0) {
        float fw = (float)img_w, fh = (float)p_img_h[0];
        float sx = fw / (float)p_in_w[0];
        float sy = fh / (float)p_in_h[0];
        float x0 = fminf(fmaxf(boxes[4*n+0] * sx, 0.f), fw);
        float y0 = fminf(fmaxf(boxes[4*n+1] * sy, 0.f), fh);
        float x1 = fminf(fmaxf(boxes[4*n+2] * sx, 0.f), fw);
        float y1 = fminf(fmaxf(boxes[4*n+3] * sy, 0.f), fh);
        sP = make_float4(x0, y0, (float)Wm / (x1 - x0), (float)Hm / (y1 - y0));
        sInvW = 1.0f / fw;
    }
    __syncthreads();
    const float4 P = sP;
    const float inv_w = sInvW;

    int g = blockIdx.x * blockDim.x + threadIdx.x;   // oct index
    int base = g * 8;
    if (base >= HW) return;

    // y = base / img_w via float reciprocal + exact correction (base < 2^24)
    int y = (int)((float)base * inv_w);
    int rem = base - y * img_w;
    if (rem < 0)            { --y; rem += img_w; }
    else if (rem >= img_w)  { ++y; rem -= img_w; }
    int x = rem;

    float* optr = out + (size_t)n * HW + base;
    const float* mb = masks + (size_t)n * Hm * Wm;

    bool fast = (((size_t)optr & 15) == 0) && (x + 7 < img_w) && (base + 7 < HW);
    if (fast) {
        float py  = ((float)y + 0.5f - P.y) * P.w - 0.5f;
        float px0 = ((float)x + 0.5f - P.x) * P.z - 0.5f;
        float px7 = px0 + 7.f * P.z;
        // P.z > 0 so px increases with x
        if (py <= -1.f || py >= (float)Hm || px7 <= -1.f || px0 >= (float)Wm) {
            float4 z = make_float4(0.f, 0.f, 0.f, 0.f);
            ((float4*)optr)[0] = z;
            ((float4*)optr)[1] = z;
        } else {
            float fy = floorf(py);
            int iy = (int)fy;
            float wy1 = py - fy, wy0 = 1.f - wy1;
            float vy0 = (iy >= 0 && iy < Hm) ? wy0 : 0.f;
            float vy1 = (iy + 1 >= 0 && iy + 1 < Hm) ? wy1 : 0.f;
            int ry0 = min(max(iy, 0), Hm - 1);
            int ry1 = min(max(iy + 1, 0), Hm - 1);
            float4 r0, r1;
            r0.x = bilin(mb, px0,            vy0, vy1, ry0, ry1, Hm, Wm);
            r0.y = bilin(mb, px0 + P.z,      vy0, vy1, ry0, ry1, Hm, Wm);
            r0.z = bilin(mb, px0 + 2.f*P.z,  vy0, vy1, ry0, ry1, Hm, Wm);
            r0.w = bilin(mb, px0 + 3.f*P.z,  vy0, vy1, ry0, ry1, Hm, Wm);
            r1.x = bilin(mb, px0 + 4.f*P.z,  vy0, vy1, ry0, ry1, Hm, Wm);
            r1.y = bilin(mb, px0 + 5.f*P.z,  vy0, vy1, ry0, ry1, Hm, Wm);
            r1.z = bilin(mb, px0 + 6.f*P.z,  vy0, vy1, ry0, ry1, Hm, Wm);
            r1.w = bilin(mb, px7,            vy0, vy1, ry0, ry1, Hm, Wm);
            ((float4*)optr)[0] = r0;
            ((float4*)optr)[1] = r1;
        }
    } else {
        // generic path: row-crossing groups, tails, unaligned
        int yy = y, xx = x;
        for (int i = 0; i < 8; ++i) {
            if (base + i >= HW) break;
            float py = ((float)yy + 0.5f - P.y) * P.w - 0.5f;
            float px = ((float)xx + 0.5f - P.x) * P.z - 0.5f;
            optr[i] = sample_one(mb, px, py, Hm, Wm);
            xx++;
            if (xx >= img_w) { xx = 0; yy++; }
        }
    }
}

extern "C" void kernel_launch(void* const* d_in, const int* in_sizes, int n_in,
                              void* d_out, int out_size, void* d_ws, size_t ws_size,
                              hipStream_t stream) {
    const float* masks  = (const float*)d_in[0];
    const float* boxes  = (const float*)d_in[1];
    const int* p_img_h  = (const int*)d_in[2];
    const int* p_img_w  = (const int*)d_in[3];
    const int* p_in_h   = (const int*)d_in[4];
    const int* p_in_w   = (const int*)d_in[5];

    int N = in_sizes[1] / 4;                 // boxes = [N,4]
    int mask_hw = in_sizes[0] / N;           // Hm*Wm
    int Wm = (int)(sqrtf((float)mask_hw) + 0.5f);
    int Hm = mask_hw / Wm;
    int HW = out_size / N;                   // img_h * img_w

    int noct = (HW + 7) / 8;
    dim3 grid((noct + TPB - 1) / TPB, 1, N);
    hipLaunchKernelGGL(paste, grid, dim3(TPB), 0, stream,
                       masks, boxes, p_img_h, p_img_w, p_in_h, p_in_w,
                       (float*)d_out, HW, Hm, Wm);
}